// Round 6
// baseline (104.497 us; speedup 1.0000x reference)
//
#include <hip/hip_runtime.h>
#include <hip/hip_bf16.h>

// BarlowTwins loss: logits[b,n,m] = sum_s z1[b,s,n]*z2[b,s,m]  (B=8, S=256, N=M=2048)
// loss = mean_{b,m}( LSE_n(logits[b,:,m]) - logits[b,m,m] )
//
// Round-6: occupancy-driven overlap. 512 blocks x 256 thr (4 waves) -> 2 blocks/CU;
// independent blocks anti-align their stage/MFMA/exp phases (m114 wave-level overlap).
//  - Block = (b, 256 m, 256 n); b = bid&7 (XCD-aligned; batch set 4MB = one L2).
//  - Wave w owns 64 m (2 strips of 32): B-frags 128 VGPR, each A-frag read feeds 2 MFMAs.
//  - Unified 8-stage dbuf pipeline: stages 0-3 stage B-tiles (wave j copies its frags at
//    stage j), stages 4-7 stage+compute A-tiles. One barrier per stage; loads 2 ahead.
//  - Staging identical for A/B (no scale): exp term = exp2(fma(acc, log2e, -96));
//    diag in natural units; merge adds ln2*96 back. No max tracking (headroom ~2^33).
//  - LDS stride 264 ushorts: write quad (lane+sg)%32, read quad (col+2ks+kg)%32 -> both
//    2-way max = free (measured 0 conflicts in rounds 2/4/5).

#define NN 2048
#define SK 256
#define LDST 264
#define LOG2E 1.4426950408889634f
#define LN2   0.6931471805599453f
#define COFF  96.0f

typedef __attribute__((ext_vector_type(8))) short short8;
typedef __attribute__((ext_vector_type(16))) float f32x16;

__device__ __forceinline__ unsigned short f2bf(float f) {
    __hip_bfloat16 h = __float2bfloat16(f);
    unsigned short u; __builtin_memcpy(&u, &h, 2); return u;
}

__device__ __forceinline__ float exp2g(float x) {
#if __has_builtin(__builtin_amdgcn_exp2f)
    return __builtin_amdgcn_exp2f(x);
#else
    return exp2f(x);
#endif
}

__device__ __forceinline__ float log2g(float x) {
#if __has_builtin(__builtin_amdgcn_logf)
    return __builtin_amdgcn_logf(x);
#else
    return log2f(x);
#endif
}

__global__ __launch_bounds__(256, 2) void gemm_lse_kernel(
    const float* __restrict__ z1, const float* __restrict__ z2,
    float* __restrict__ ws_sum, float* __restrict__ ws_diag)
{
    __shared__ unsigned short lds[2][64 * LDST];   // 67.6 KB -> 2 blocks/CU

    const int bid  = blockIdx.x;
    const int b    = bid & 7;          // XCD-aligned batch
    const int tile = bid >> 3;         // 0..63
    const int mb   = tile & 7;         // m-block of 256
    const int ns   = tile >> 3;        // n-split of 256
    const int tid  = threadIdx.x;
    const int lane = tid & 63;
    const int w    = tid >> 6;         // wave 0..3
    const int col  = lane & 31;
    const int kg   = lane >> 5;

    const int m0 = mb * 256 + w * 64;  // strip0; strip1 = +32
    const int n0 = ns * 256;

    const float* z1b = z1 + (size_t)b * SK * NN;
    const float* z2b = z2 + (size_t)b * SK * NN;

    // ---- cooperative tile staging: 64 cols x 256 s, f32 -> bf16 -> LDS[col][s] ----
    float apf[8][8];
    auto load_T = [&](const float* src, int cbase) {
        #pragma unroll
        for (int r = 0; r < 8; ++r) {
            const int sg = 4 * r + w;  // s-group 0..31 (8 s each)
            const float* p = src + (size_t)(sg * 8) * NN + cbase + lane;
            #pragma unroll
            for (int j = 0; j < 8; ++j) apf[r][j] = p[(size_t)j * NN];
        }
    };
    auto store_T = [&](unsigned short* buf) {
        #pragma unroll
        for (int r = 0; r < 8; ++r) {
            const int sg = 4 * r + w;
            short8 pk;
            #pragma unroll
            for (int j = 0; j < 8; ++j) pk[j] = (short)f2bf(apf[r][j]);
            *(short8*)(buf + lane * LDST + sg * 8) = pk;
        }
    };
    // tile i: 0..3 = B-tiles (z2 cols mb*256+i*64), 4..7 = A-tiles (z1 cols n0+(i-4)*64)
    auto load_tile = [&](int i) {
        if (i < 4) load_T(z2b, mb * 256 + i * 64);
        else       load_T(z1b, n0 + (i - 4) * 64);
    };

    short8 bf0[16], bf1[16];
    float srun0 = 0.0f, srun1 = 0.0f;

    // prologue: tiles 0,1
    load_tile(0);
    store_T(lds[0]);
    load_tile(1);
    __syncthreads();

    #pragma unroll
    for (int i = 0; i < 8; ++i) {
        if (i < 4) {
            // B-stage: wave i copies its 2 strips of fragments out of buf(i&1)
            if (w == i) {
                const unsigned short* b0 = lds[i & 1] + col * LDST + kg * 8;
                #pragma unroll
                for (int ks = 0; ks < 16; ++ks) {
                    bf0[ks] = *(const short8*)(b0 + ks * 16);
                    bf1[ks] = *(const short8*)(b0 + 32 * LDST + ks * 16);
                }
            }
            if (i < 7) store_T(lds[(i + 1) & 1]);
            load_tile(i + 2);
        } else {
            // A-stage: two 32-n halves; store/load pipelined between the halves
            const int t = i - 4;
            #pragma unroll
            for (int half = 0; half < 2; ++half) {
                const unsigned short* abase = lds[i & 1] + (32 * half + col) * LDST + kg * 8;

                f32x16 acc0, acc1;
                #pragma unroll
                for (int r = 0; r < 16; ++r) { acc0[r] = 0.0f; acc1[r] = 0.0f; }

                #pragma unroll
                for (int ks = 0; ks < 16; ++ks) {
                    short8 af = *(const short8*)(abase + ks * 16);
                    acc0 = __builtin_amdgcn_mfma_f32_32x32x16_bf16(af, bf0[ks], acc0, 0, 0, 0);
                    acc1 = __builtin_amdgcn_mfma_f32_32x32x16_bf16(af, bf1[ks], acc1, 0, 0, 0);
                }

                if (half == 0) {           // stage next tile while acc-postprocess runs
                    if (i < 7) { store_T(lds[(i + 1) & 1]); }
                    if (i < 6) { load_tile(i + 2); }
                }

                // diagonal capture (natural units)
                const int nsub = n0 + t * 64 + 32 * half;
                if (nsub == m0) {
                    #pragma unroll
                    for (int r = 0; r < 16; ++r) {
                        const int row = (r & 3) + 8 * (r >> 2) + 4 * kg;
                        if (row == col) ws_diag[b * NN + m0 + col] = acc0[r];
                    }
                }
                if (nsub == m0 + 32) {
                    #pragma unroll
                    for (int r = 0; r < 16; ++r) {
                        const int row = (r & 3) + 8 * (r >> 2) + 4 * kg;
                        if (row == col) ws_diag[b * NN + m0 + 32 + col] = acc1[r];
                    }
                }

                // exp2-sum: term = 2^(acc*log2e - 96); 4 independent chains per strip
                {
                    float e0 = 0, e1 = 0, e2 = 0, e3 = 0;
                    #pragma unroll
                    for (int r = 0; r < 16; r += 4) {
                        e0 += exp2g(fmaf(acc0[r],     LOG2E, -COFF));
                        e1 += exp2g(fmaf(acc0[r + 1], LOG2E, -COFF));
                        e2 += exp2g(fmaf(acc0[r + 2], LOG2E, -COFF));
                        e3 += exp2g(fmaf(acc0[r + 3], LOG2E, -COFF));
                    }
                    srun0 += (e0 + e1) + (e2 + e3);
                }
                {
                    float e0 = 0, e1 = 0, e2 = 0, e3 = 0;
                    #pragma unroll
                    for (int r = 0; r < 16; r += 4) {
                        e0 += exp2g(fmaf(acc1[r],     LOG2E, -COFF));
                        e1 += exp2g(fmaf(acc1[r + 1], LOG2E, -COFF));
                        e2 += exp2g(fmaf(acc1[r + 2], LOG2E, -COFF));
                        e3 += exp2g(fmaf(acc1[r + 3], LOG2E, -COFF));
                    }
                    srun1 += (e0 + e1) + (e2 + e3);
                }
            }
        }
        __syncthreads();
    }

    srun0 += __shfl_xor(srun0, 32);
    srun1 += __shfl_xor(srun1, 32);
    if (kg == 0) {
        ws_sum[(b * 8 + ns) * NN + m0 + col]      = srun0;
        ws_sum[(b * 8 + ns) * NN + m0 + 32 + col] = srun1;
    }
}

__global__ __launch_bounds__(256) void merge_kernel(
    const float* __restrict__ ws_sum, const float* __restrict__ ws_diag,
    float* __restrict__ partial)
{
    const int gid = blockIdx.x * 256 + threadIdx.x;   // 0..16383
    const int b = gid >> 11, m = gid & (NN - 1);

    float S = 0.0f;
    #pragma unroll
    for (int slot = 0; slot < 8; ++slot)
        S += ws_sum[(b * 8 + slot) * NN + m];
    // LSE - diag = ln2*(log2(S) + 96) - diag   (natural units)
    float c = fmaf(LN2, log2g(S) + COFF, -ws_diag[gid]);

    #pragma unroll
    for (int d = 1; d < 64; d <<= 1) c += __shfl_xor(c, d);
    __shared__ float red[4];
    if ((threadIdx.x & 63) == 0) red[threadIdx.x >> 6] = c;
    __syncthreads();
    if (threadIdx.x == 0)
        partial[blockIdx.x] = red[0] + red[1] + red[2] + red[3];
}

__global__ void final_kernel(const float* __restrict__ partial, float* __restrict__ out)
{
    float v = partial[threadIdx.x];   // 64 threads
    #pragma unroll
    for (int d = 1; d < 64; d <<= 1) v += __shfl_xor(v, d);
    if (threadIdx.x == 0) out[0] = v / 16384.0f;
}

extern "C" void kernel_launch(void* const* d_in, const int* in_sizes, int n_in,
                              void* d_out, int out_size, void* d_ws, size_t ws_size,
                              hipStream_t stream)
{
    const float* z1 = (const float*)d_in[0];
    const float* z2 = (const float*)d_in[1];
    float* ws  = (float*)d_ws;
    float* out = (float*)d_out;

    // ws layout (floats): sum[8][8][2048] | diag[8][2048] | partial[64]
    float* ws_sum  = ws;
    float* ws_diag = ws + 131072;
    float* ws_part = ws + 147456;

    gemm_lse_kernel<<<dim3(512), dim3(256), 0, stream>>>(z1, z2, ws_sum, ws_diag);
    merge_kernel<<<dim3(64), dim3(256), 0, stream>>>(ws_sum, ws_diag, ws_part);
    final_kernel<<<dim3(1), dim3(64), 0, stream>>>(ws_part, out);
}